// Round 18
// baseline (178.983 us; speedup 1.0000x reference)
//
#include <hip/hip_runtime.h>
#include <hip/hip_bf16.h>

// S4D regressor, chunked-scan MFMA formulation.
// R18: R17 (green, 176.7 us) + final safe vectorization sweep:
//  (a) stats: short8 (16B) loads, 512-l blocks (half the dispatch count);
//  (b) ln3: short8 loads;
//  (c) ks: phase-3a hoisted above phase-1's fence (xf/W2l-only deps).
// All bit-identical numerics. B=32, L=4096, C=128, N=64, DEPTH=4, OUT=1.

#define BB     32
#define LL     4096
#define CC     128
#define NN     64
#define DEPTH_ 4
#define EPSV   1e-5f

typedef __attribute__((ext_vector_type(8))) short short8;
typedef __attribute__((ext_vector_type(4))) short short4v;
typedef __attribute__((ext_vector_type(4))) float f32x4;
typedef __hip_bfloat16 bf16;

#define MFMA(a, b, c) __builtin_amdgcn_mfma_f32_16x16x32_bf16(a, b, c, 0, 0, 0)

__device__ __forceinline__ bf16 tobf(float x) { return __float2bfloat16(x); }
__device__ __forceinline__ short bfbits(float x) {
    union { bf16 b; short s; } u; u.b = __float2bfloat16(x); return u.s;
}
__device__ __forceinline__ float frombits(short s) {
    return __uint_as_float(((uint)(ushort)s) << 16);
}

// ---------------------------------------------------------------------------
// P0: per (d,c,n): lam=exp(dt*A), dta=dt*A, cb2=2*C*(lam-1)/A, lamT=lam^64
// ---------------------------------------------------------------------------
__global__ __launch_bounds__(64) void p0_kernel(
    const float* __restrict__ log_dt, const float* __restrict__ A_real,
    const float* __restrict__ A_imag, const float* __restrict__ C_re,
    const float* __restrict__ C_im, float2* __restrict__ lam,
    float2* __restrict__ dta, float2* __restrict__ cb2,
    float2* __restrict__ lamT)
{
    int d = blockIdx.y, c = blockIdx.x, n = threadIdx.x;
    int idx = (d * CC + c) * NN + n;
    float dt  = expf(log_dt[d * CC + c]);
    float Ar  = -expf(A_real[idx]);
    float Ai  = A_imag[idx];
    float dtr = dt * Ar, dti = dt * Ai;
    float e   = expf(dtr);
    float lr  = e * cosf(dti), li = e * sinf(dti);
    float m    = Ar * Ar + Ai * Ai;
    float inv  = 1.0f / m;
    float numr = lr - 1.0f, numi = li;
    float br   = (numr * Ar + numi * Ai) * inv;
    float bi   = (numi * Ar - numr * Ai) * inv;
    float cre  = C_re[idx], cim = C_im[idx];
    lam[idx]  = make_float2(lr, li);
    dta[idx]  = make_float2(dtr, dti);
    cb2[idx]  = make_float2(2.0f * (cre * br - cim * bi),
                            2.0f * (cre * bi + cim * br));
    float eT = expf(64.0f * dtr);
    lamT[idx] = make_float2(eT * cosf(64.0f * dti), eT * sinf(64.0f * dti));
}

// ---------------------------------------------------------------------------
// P1: Kloc[d][c][delta] = Re sum_n cb2_n lam_n^delta   (delta = 0..63)
// ---------------------------------------------------------------------------
__global__ __launch_bounds__(64) void p1_kernel(
    const float2* __restrict__ cb2, const float2* __restrict__ lam,
    float* __restrict__ Kloc)
{
    __shared__ float st[64 * 65];
    int d = blockIdx.y, c = blockIdx.x, n = threadIdx.x;
    float2 p = cb2[(d * CC + c) * NN + n];
    float2 l = lam[(d * CC + c) * NN + n];
    for (int t = 0; t < 64; ++t) {
        st[t * 65 + n] = p.x;
        float nr = p.x * l.x - p.y * l.y;
        p.y = p.x * l.y + p.y * l.x;
        p.x = nr;
    }
    __syncthreads();
    float s = 0.0f;
#pragma unroll 16
    for (int j = 0; j < 64; ++j) s += st[n * 65 + j];
    Kloc[(d * CC + c) * 64 + n] = s;
}

// ---------------------------------------------------------------------------
// P2 (merged): blocks [0, 16384) build Vp; [16384, 40960) build W2p.
// ---------------------------------------------------------------------------
__global__ __launch_bounds__(256) void p2_kernel(
    const float2* __restrict__ dta, const float2* __restrict__ cb2,
    const float* __restrict__ Kloc, const float* __restrict__ Dskip,
    bf16* __restrict__ Vp, bf16* __restrict__ W2p)
{
    int bid = blockIdx.x;
    if (bid < (DEPTH_ * CC * 8192) / 256) {
        int t = bid * 256 + threadIdx.x;
        int e = t & 7, l = (t >> 3) & 63, ks = (t >> 9) & 1;
        int nf = (t >> 10) & 7, c = (t >> 13) & 127, d = t >> 20;
        int q = nf * 16 + (l & 15);
        int k = ks * 32 + (l >> 4) * 8 + e;
        int n = q >> 1;
        float2 a = dta[(d * CC + c) * NN + n];
        float p  = (float)(63 - k);
        float mag = expf(p * a.x);
        float ang = p * a.y;
        float val = (q & 1) ? mag * sinf(ang) : mag * cosf(ang);
        Vp[t] = tobf(val);
    } else {
        int t = (bid - (DEPTH_ * CC * 8192) / 256) * 256 + threadIdx.x;
        int e = t & 7, l = (t >> 3) & 63;
        int r = t >> 9;
        int ks = r % 6; r /= 6;
        int nf = r & 3; r >>= 2;
        int c  = r & 127;
        int d  = r >> 7;
        int i = nf * 16 + (l & 15);
        int k = ks * 32 + (l >> 4) * 8 + e;
        float val;
        if (k < 64) {
            val = (k <= i) ? Kloc[(d * CC + c) * 64 + (i - k)] : 0.0f;
            if (k == i) val += Dskip[d * CC + c] + 1.0f;
        } else {
            int q = k - 64, n = q >> 1;
            float2 a  = dta[(d * CC + c) * NN + n];
            float2 cb = cb2[(d * CC + c) * NN + n];
            float p   = (float)(i + 1);
            float mag = expf(p * a.x);
            float ang = p * a.y;
            float re = mag * cosf(ang), im = mag * sinf(ang);
            float wre = cb.x * re - cb.y * im;
            float wim = cb.x * im + cb.y * re;
            val = (q & 1) ? -wim : wre;
        }
        W2p[t] = tobf(val);
    }
}

// ---------------------------------------------------------------------------
// x [B,L,C] fp32 -> xt [B][C][L] bf16
// ---------------------------------------------------------------------------
__global__ __launch_bounds__(256) void transpose_kernel(
    const float* __restrict__ x, bf16* __restrict__ xt)
{
    __shared__ float t[64][65];
    int ct = blockIdx.x, lt = blockIdx.y, b = blockIdx.z;
    int tx = threadIdx.x & 63, ty = threadIdx.x >> 6;
    const size_t xbase = ((size_t)b * LL + (size_t)lt * 64) * CC + (size_t)ct * 64;
#pragma unroll
    for (int i = 0; i < 16; ++i)
        t[ty + 4 * i][tx] = x[xbase + (size_t)(ty + 4 * i) * CC + tx];
    __syncthreads();
    const size_t obase = ((size_t)b * CC + (size_t)ct * 64) * LL + (size_t)lt * 64;
#pragma unroll
    for (int i = 0; i < 16; ++i)
        xt[obase + (size_t)(ty + 4 * i) * LL + tx] = tobf(t[tx][ty + 4 * i]);
}

// ---------------------------------------------------------------------------
// STATS: per-(b,l) LayerNorm statistics; short8 loads, 512 l's per block.
// ---------------------------------------------------------------------------
__global__ __launch_bounds__(256) void stats_kernel(
    const bf16* __restrict__ v, float2* __restrict__ st)
{
    __shared__ float rs[4][512];
    __shared__ float rq[4][512];
    int b  = blockIdx.y;
    int l0 = blockIdx.x * 512;
    int lt = threadIdx.x & 63;
    int cg = threadIdx.x >> 6;
    const short* vv = (const short*)v;
    float s[8] = {0.f, 0.f, 0.f, 0.f, 0.f, 0.f, 0.f, 0.f};
    float q[8] = {0.f, 0.f, 0.f, 0.f, 0.f, 0.f, 0.f, 0.f};
#pragma unroll
    for (int ci = 0; ci < 32; ++ci) {
        int c = cg * 32 + ci;
        short8 r = *(const short8*)(&vv[((size_t)b * CC + c) * LL + l0 + lt * 8]);
#pragma unroll
        for (int j = 0; j < 8; ++j) {
            float f = frombits(r[j]);
            s[j] += f;
            q[j] = fmaf(f, f, q[j]);
        }
    }
#pragma unroll
    for (int j = 0; j < 8; ++j) {
        rs[cg][lt * 8 + j] = s[j];
        rq[cg][lt * 8 + j] = q[j];
    }
    __syncthreads();
    if (cg < 2) {
#pragma unroll
        for (int j = 0; j < 4; ++j) {
            int li = cg * 256 + lt * 4 + j;
            float ts = rs[0][li] + rs[1][li] + rs[2][li] + rs[3][li];
            float tq = rq[0][li] + rq[1][li] + rq[2][li] + rq[3][li];
            float mean = ts * (1.0f / CC);
            float var  = tq * (1.0f / CC) - mean * mean;
            st[(size_t)b * LL + l0 + li] = make_float2(mean, rsqrtf(var + EPSV));
        }
    }
}

// ---------------------------------------------------------------------------
// KS: block = (c, 8 b's), 512 threads. Weights (40 KB) staged in LDS once.
// Per group: normalize -> phase3a (xf-only, hoisted) -> phase1 -> prefetch ->
// batched scan -> phase3b -> store. One barrier total.
// ---------------------------------------------------------------------------
__global__ __launch_bounds__(512) void ks_kernel(
    const bf16* __restrict__ u, bf16* __restrict__ v,
    const bf16* __restrict__ Vp, const bf16* __restrict__ W2p,
    const float2* __restrict__ lamT, const float2* __restrict__ st,
    const float* __restrict__ nw, const float* __restrict__ nb)
{
    const int c  = blockIdx.x;             // channel owned by this block
    const int w  = threadIdx.x >> 6;       // wave 0..7 -> b = bg*8+w
    const int l  = threadIdx.x & 63;       // lane: MFMA lane AND mode index n
    const int b  = blockIdx.y * 8 + w;
    const int bc = b * CC + c;
    const bf16* xrow = u + (size_t)bc * LL;
    bf16*       vrow = v + (size_t)bc * LL;

    __shared__ short Wl[8192 + 12288];     // Vp(16KB) + W2p(24KB) = 40 KB
    __shared__ short Sp[8][16 * 136];      // per-wave 4.35 KB scan slice

    // ---- stage weights: 2560 x uint4 across 512 threads, one barrier ----
    {
        uint4*       dst  = (uint4*)Wl;
        const uint4* srcV = (const uint4*)(Vp  + (size_t)c * 8192);
        const uint4* srcW = (const uint4*)(W2p + (size_t)c * 12288);
        int tid = threadIdx.x;
#pragma unroll
        for (int i = 0; i < 2; ++i)
            dst[tid + 512 * i] = srcV[tid + 512 * i];
#pragma unroll
        for (int i = 0; i < 3; ++i)
            dst[1024 + tid + 512 * i] = srcW[tid + 512 * i];
    }
    __syncthreads();                       // the ONLY barrier

    short* S = Sp[w];
    const short* W2l = Wl + 8192;
    const int mloc = l & 15;               // chunk-within-group (MFMA B-col)
    const int koff = (l >> 4) * 8;
    float2 lt = lamT[c * NN + l];
    float sr = 0.f, si = 0.f;              // running state, f32 entire L

    const float2* stb = st ? (st + (size_t)b * LL) : nullptr;
    float wc = 0.f, bcf = 0.f;
    if (st) { wc = nw[c]; bcf = nb[c]; }

    // ---- prefetch group 0's raw x fragments ----
    short8 xf0 = *(const short8*)(xrow + mloc * 64 + koff);
    short8 xf1 = *(const short8*)(xrow + mloc * 64 + koff + 32);

#pragma unroll 1
    for (int g = 0; g < 4; ++g) {
        const int lbase = (g * 16 + mloc) * 64 + koff;

        // ---- normalize current fragments (float4 stat loads) ----
        if (stb) {
            const float4* sq0 = (const float4*)(stb + lbase);
            const float4* sq1 = (const float4*)(stb + lbase + 32);
#pragma unroll
            for (int i = 0; i < 4; ++i) {
                float4 p0 = sq0[i], p1 = sq1[i];
                float a00 = p0.y * wc, a01 = p0.w * wc;
                float a10 = p1.y * wc, a11 = p1.w * wc;
                xf0[2 * i]     = bfbits(fmaf(frombits(xf0[2 * i]),     a00, fmaf(-p0.x, a00, bcf)));
                xf0[2 * i + 1] = bfbits(fmaf(frombits(xf0[2 * i + 1]), a01, fmaf(-p0.z, a01, bcf)));
                xf1[2 * i]     = bfbits(fmaf(frombits(xf1[2 * i]),     a10, fmaf(-p1.x, a10, bcf)));
                xf1[2 * i + 1] = bfbits(fmaf(frombits(xf1[2 * i + 1]), a11, fmaf(-p1.z, a11, bcf)));
            }
        }

        // ---- phase 3a (hoisted): ks=0,1 MFMAs — xf/W2l only ----
        f32x4 o[4];
#pragma unroll
        for (int nf = 0; nf < 4; ++nf) o[nf] = (f32x4){0.f, 0.f, 0.f, 0.f};
#pragma unroll
        for (int nf = 0; nf < 4; ++nf) {
            short8 wf0 = *(const short8*)(&W2l[((nf * 6 + 0) * 64 + l) * 8]);
            o[nf] = MFMA(wf0, xf0, o[nf]);
            short8 wf1 = *(const short8*)(&W2l[((nf * 6 + 1) * 64 + l) * 8]);
            o[nf] = MFMA(wf1, xf1, o[nf]);
        }

        // ---- phase 1 (two 4-nf halves to cap acc pressure) ----
#pragma unroll
        for (int h = 0; h < 2; ++h) {
            f32x4 acc[4];
#pragma unroll
            for (int j = 0; j < 4; ++j) acc[j] = (f32x4){0.f, 0.f, 0.f, 0.f};
#pragma unroll
            for (int j = 0; j < 4; ++j) {
                int nf = h * 4 + j;
                short8 vf0 = *(const short8*)(&Wl[((nf * 2 + 0) * 64 + l) * 8]);
                short8 vf1 = *(const short8*)(&Wl[((nf * 2 + 1) * 64 + l) * 8]);
                acc[j] = MFMA(vf0, xf0, acc[j]);
                acc[j] = MFMA(vf1, xf1, acc[j]);
            }
#pragma unroll
            for (int j = 0; j < 4; ++j) {
                int nf = h * 4 + j;
                short4v t;
                t[0] = bfbits(acc[j][0]); t[1] = bfbits(acc[j][1]);
                t[2] = bfbits(acc[j][2]); t[3] = bfbits(acc[j][3]);
                *(short4v*)(&S[mloc * 136 + nf * 16 + (l >> 4) * 4]) = t;
            }
        }
        asm volatile("" ::: "memory");     // same-wave DS pipe is in-order

        // ---- prefetch next group's raw x fragments ----
        const int gn = (g < 3) ? g + 1 : 3;
        const int lbn = (gn * 16 + mloc) * 64 + koff;
        short8 nxf0 = *(const short8*)(xrow + lbn);
        short8 nxf1 = *(const short8*)(xrow + lbn + 32);

        // ---- scan: batched reads -> VALU chain -> batched writes ----
        uint pk[16];
#pragma unroll
        for (int k = 0; k < 16; ++k)
            pk[k] = *(const uint*)(&S[k * 136 + 2 * l]);
#pragma unroll
        for (int k = 0; k < 16; ++k) {
            uint p = pk[k];
            union { short2 s2; uint uu; } o2;
            o2.s2.x = bfbits(sr); o2.s2.y = bfbits(si);
            pk[k] = o2.uu;                 // Sprev for chunk k
            float pr = __uint_as_float(p << 16);
            float pi = __uint_as_float(p & 0xffff0000u);
            float nr = fmaf(lt.x, sr, fmaf(-lt.y, si, pr));
            si = fmaf(lt.x, si, fmaf(lt.y, sr, pi));
            sr = nr;
        }
#pragma unroll
        for (int k = 0; k < 16; ++k)
            *(uint*)(&S[k * 136 + 2 * l]) = pk[k];
        asm volatile("" ::: "memory");

        // ---- phase 3b: ks=2..5 from Sprev ----
#pragma unroll
        for (int ks = 2; ks < 6; ++ks) {
            short8 xf = *(const short8*)(&S[mloc * 136 + (ks - 2) * 32 + koff]);
#pragma unroll
            for (int nf = 0; nf < 4; ++nf) {
                short8 wf = *(const short8*)(&W2l[((nf * 6 + ks) * 64 + l) * 8]);
                o[nf] = MFMA(wf, xf, o[nf]);
            }
        }
#pragma unroll
        for (int nf = 0; nf < 4; ++nf) {
            short4v t;
            t[0] = bfbits(o[nf][0]); t[1] = bfbits(o[nf][1]);
            t[2] = bfbits(o[nf][2]); t[3] = bfbits(o[nf][3]);
            *(short4v*)(vrow + (g * 16 + mloc) * 64 + nf * 16 + (l >> 4) * 4) = t;
        }

        xf0 = nxf0;                        // rotate prefetched fragments
        xf1 = nxf1;
    }
}

// ---------------------------------------------------------------------------
// LN3: final LayerNorm + head in ONE pass; short8 loads.
//   out[b,l] = rstd*( sum_c v*wh_c - mu*S1 ) + S2
// ---------------------------------------------------------------------------
__global__ __launch_bounds__(256) void ln3_kernel(
    const bf16* __restrict__ v,
    const float* __restrict__ w, const float* __restrict__ bta,
    const float* __restrict__ headw, const float* __restrict__ headb,
    float* __restrict__ fout)
{
    __shared__ float rs[4][512];
    __shared__ float rq[4][512];
    __shared__ float rh[4][512];
    __shared__ float r1s[4];
    __shared__ float r2s[4];
    int b  = blockIdx.y;
    int l0 = blockIdx.x * 512;
    int lt = threadIdx.x & 63;
    int cg = threadIdx.x >> 6;
    const short* vv = (const short*)v;
    float s[8] = {0.f, 0.f, 0.f, 0.f, 0.f, 0.f, 0.f, 0.f};
    float q[8] = {0.f, 0.f, 0.f, 0.f, 0.f, 0.f, 0.f, 0.f};
    float h[8] = {0.f, 0.f, 0.f, 0.f, 0.f, 0.f, 0.f, 0.f};
    float ps1 = 0.f, ps2 = 0.f;
#pragma unroll
    for (int ci = 0; ci < 32; ++ci) {
        int c = cg * 32 + ci;
        float hwc = headw[c];
        float whc = w[c] * hwc;
        ps1 += whc;
        ps2 = fmaf(bta[c], hwc, ps2);
        short8 r = *(const short8*)(&vv[((size_t)b * CC + c) * LL + l0 + lt * 8]);
#pragma unroll
        for (int j = 0; j < 8; ++j) {
            float f = frombits(r[j]);
            s[j] += f;
            q[j] = fmaf(f, f, q[j]);
            h[j] = fmaf(f, whc, h[j]);
        }
    }
#pragma unroll
    for (int j = 0; j < 8; ++j) {
        rs[cg][lt * 8 + j] = s[j];
        rq[cg][lt * 8 + j] = q[j];
        rh[cg][lt * 8 + j] = h[j];
    }
    if (lt == 0) { r1s[cg] = ps1; r2s[cg] = ps2; }
    __syncthreads();
    if (cg < 2) {
        float S1 = r1s[0] + r1s[1] + r1s[2] + r1s[3];
        float S2 = r2s[0] + r2s[1] + r2s[2] + r2s[3] + headb[0];
#pragma unroll
        for (int j = 0; j < 4; ++j) {
            int li = cg * 256 + lt * 4 + j;
            float ts = rs[0][li] + rs[1][li] + rs[2][li] + rs[3][li];
            float tq = rq[0][li] + rq[1][li] + rq[2][li] + rq[3][li];
            float th = rh[0][li] + rh[1][li] + rh[2][li] + rh[3][li];
            float mean = ts * (1.0f / CC);
            float var  = tq * (1.0f / CC) - mean * mean;
            float rstd = rsqrtf(var + EPSV);
            fout[(size_t)b * LL + l0 + li] = rstd * (th - mean * S1) + S2;
        }
    }
}

// ---------------------------------------------------------------------------
extern "C" void kernel_launch(void* const* d_in, const int* in_sizes, int n_in,
                              void* d_out, int out_size, void* d_ws, size_t ws_size,
                              hipStream_t stream)
{
    const float* x      = (const float*)d_in[0];
    const float* log_dt = (const float*)d_in[1];
    const float* A_real = (const float*)d_in[2];
    const float* A_imag = (const float*)d_in[3];
    const float* C_re   = (const float*)d_in[4];
    const float* C_im   = (const float*)d_in[5];
    const float* Dskip  = (const float*)d_in[6];
    const float* norm_w = (const float*)d_in[7];
    const float* norm_b = (const float*)d_in[8];
    const float* head_w = (const float*)d_in[9];
    const float* head_b = (const float*)d_in[10];
    float* out = (float*)d_out;

    const size_t DCN = (size_t)DEPTH_ * CC * NN;
    const size_t BCL = (size_t)BB * CC * LL;

    float2* lam  = (float2*)d_ws;
    float2* dta  = lam + DCN;
    float2* cb2  = dta + DCN;
    float2* lamT = cb2 + DCN;
    float*  Kloc = (float*)(lamT + DCN);
    bf16*   A    = (bf16*)(Kloc + (size_t)DEPTH_ * CC * 64);
    bf16*   Bb   = A + BCL;
    bf16*   Vp   = Bb + BCL;
    bf16*   W2p  = Vp + (size_t)DEPTH_ * CC * 8192;
    float2* stbuf = (float2*)(W2p + (size_t)DEPTH_ * CC * 12288);  // B*L float2

    p0_kernel<<<dim3(CC, DEPTH_), 64, 0, stream>>>(
        log_dt, A_real, A_imag, C_re, C_im, lam, dta, cb2, lamT);
    p1_kernel<<<dim3(CC, DEPTH_), 64, 0, stream>>>(cb2, lam, Kloc);
    p2_kernel<<<(DEPTH_ * CC * 8192) / 256 + (DEPTH_ * CC * 12288) / 256,
                256, 0, stream>>>(dta, cb2, Kloc, Dskip, Vp, W2p);
    transpose_kernel<<<dim3(CC / 64, LL / 64, BB), 256, 0, stream>>>(x, A);

    // d=0: A -> Bb (no input norm)
    ks_kernel<<<dim3(CC, BB / 8), 512, 0, stream>>>(
        A, Bb, Vp, W2p, lamT, nullptr, nullptr, nullptr);
    // middle layers: stats then normalized ks
    bf16* src = Bb;
    bf16* dst = A;
    for (int d = 1; d < DEPTH_; ++d) {
        stats_kernel<<<dim3(LL / 512, BB), 256, 0, stream>>>(src, stbuf);
        ks_kernel<<<dim3(CC, BB / 8), 512, 0, stream>>>(
            src, dst, Vp + (size_t)d * CC * 8192, W2p + (size_t)d * CC * 12288,
            lamT + (size_t)d * CC * NN, stbuf,
            norm_w + (d - 1) * CC, norm_b + (d - 1) * CC);
        bf16* tmp = src; src = dst; dst = tmp;
    }
    // final LN + head, one pass
    ln3_kernel<<<dim3(LL / 512, BB), 256, 0, stream>>>(
        src, norm_w + (DEPTH_ - 1) * CC, norm_b + (DEPTH_ - 1) * CC,
        head_w, head_b, out);
}

// Round 19
// 177.289 us; speedup vs baseline: 1.0096x; 1.0096x over previous
//
#include <hip/hip_runtime.h>
#include <hip/hip_bf16.h>

// S4D regressor, chunked-scan MFMA formulation.
// R19 = R17 verbatim (session-best green: 176.7 us, absmax 0.03125).
// R18's stats/ln3 widening was neutral-to-negative; reverted.
// Structure: precompute -> transpose -> [ks (LDS-staged weights, 8-wave,
// LN fused via stats) x4] -> one-pass final LN+head.
// Plateau analysis: ks is LDS-throughput-bound (2560 ds_read_b128/CU of
// weight fragments); the escape (cross-group weight reuse, R13/R14) failed
// correctness twice and the LDS-weights variant needs 179KB > 160KB.
// B=32, L=4096, C=128, N=64, DEPTH=4, OUT=1.

#define BB     32
#define LL     4096
#define CC     128
#define NN     64
#define DEPTH_ 4
#define EPSV   1e-5f

typedef __attribute__((ext_vector_type(8))) short short8;
typedef __attribute__((ext_vector_type(4))) short short4v;
typedef __attribute__((ext_vector_type(4))) float f32x4;
typedef __hip_bfloat16 bf16;

#define MFMA(a, b, c) __builtin_amdgcn_mfma_f32_16x16x32_bf16(a, b, c, 0, 0, 0)

__device__ __forceinline__ bf16 tobf(float x) { return __float2bfloat16(x); }
__device__ __forceinline__ short bfbits(float x) {
    union { bf16 b; short s; } u; u.b = __float2bfloat16(x); return u.s;
}
__device__ __forceinline__ float frombits(short s) {
    return __uint_as_float(((uint)(ushort)s) << 16);
}

// ---------------------------------------------------------------------------
// P0: per (d,c,n): lam=exp(dt*A), dta=dt*A, cb2=2*C*(lam-1)/A, lamT=lam^64
// ---------------------------------------------------------------------------
__global__ __launch_bounds__(64) void p0_kernel(
    const float* __restrict__ log_dt, const float* __restrict__ A_real,
    const float* __restrict__ A_imag, const float* __restrict__ C_re,
    const float* __restrict__ C_im, float2* __restrict__ lam,
    float2* __restrict__ dta, float2* __restrict__ cb2,
    float2* __restrict__ lamT)
{
    int d = blockIdx.y, c = blockIdx.x, n = threadIdx.x;
    int idx = (d * CC + c) * NN + n;
    float dt  = expf(log_dt[d * CC + c]);
    float Ar  = -expf(A_real[idx]);
    float Ai  = A_imag[idx];
    float dtr = dt * Ar, dti = dt * Ai;
    float e   = expf(dtr);
    float lr  = e * cosf(dti), li = e * sinf(dti);
    float m    = Ar * Ar + Ai * Ai;
    float inv  = 1.0f / m;
    float numr = lr - 1.0f, numi = li;
    float br   = (numr * Ar + numi * Ai) * inv;
    float bi   = (numi * Ar - numr * Ai) * inv;
    float cre  = C_re[idx], cim = C_im[idx];
    lam[idx]  = make_float2(lr, li);
    dta[idx]  = make_float2(dtr, dti);
    cb2[idx]  = make_float2(2.0f * (cre * br - cim * bi),
                            2.0f * (cre * bi + cim * br));
    float eT = expf(64.0f * dtr);
    lamT[idx] = make_float2(eT * cosf(64.0f * dti), eT * sinf(64.0f * dti));
}

// ---------------------------------------------------------------------------
// P1: Kloc[d][c][delta] = Re sum_n cb2_n lam_n^delta   (delta = 0..63)
// ---------------------------------------------------------------------------
__global__ __launch_bounds__(64) void p1_kernel(
    const float2* __restrict__ cb2, const float2* __restrict__ lam,
    float* __restrict__ Kloc)
{
    __shared__ float st[64 * 65];
    int d = blockIdx.y, c = blockIdx.x, n = threadIdx.x;
    float2 p = cb2[(d * CC + c) * NN + n];
    float2 l = lam[(d * CC + c) * NN + n];
    for (int t = 0; t < 64; ++t) {
        st[t * 65 + n] = p.x;
        float nr = p.x * l.x - p.y * l.y;
        p.y = p.x * l.y + p.y * l.x;
        p.x = nr;
    }
    __syncthreads();
    float s = 0.0f;
#pragma unroll 16
    for (int j = 0; j < 64; ++j) s += st[n * 65 + j];
    Kloc[(d * CC + c) * 64 + n] = s;
}

// ---------------------------------------------------------------------------
// P2 (merged): blocks [0, 16384) build Vp; [16384, 40960) build W2p.
// Vp packed [d][c][nf=8][ks=2][lane=64][e=8]; W2p [d][c][nf=4][ks=6][64][8].
// ---------------------------------------------------------------------------
__global__ __launch_bounds__(256) void p2_kernel(
    const float2* __restrict__ dta, const float2* __restrict__ cb2,
    const float* __restrict__ Kloc, const float* __restrict__ Dskip,
    bf16* __restrict__ Vp, bf16* __restrict__ W2p)
{
    int bid = blockIdx.x;
    if (bid < (DEPTH_ * CC * 8192) / 256) {
        int t = bid * 256 + threadIdx.x;
        int e = t & 7, l = (t >> 3) & 63, ks = (t >> 9) & 1;
        int nf = (t >> 10) & 7, c = (t >> 13) & 127, d = t >> 20;
        int q = nf * 16 + (l & 15);
        int k = ks * 32 + (l >> 4) * 8 + e;
        int n = q >> 1;
        float2 a = dta[(d * CC + c) * NN + n];
        float p  = (float)(63 - k);
        float mag = expf(p * a.x);
        float ang = p * a.y;
        float val = (q & 1) ? mag * sinf(ang) : mag * cosf(ang);
        Vp[t] = tobf(val);
    } else {
        int t = (bid - (DEPTH_ * CC * 8192) / 256) * 256 + threadIdx.x;
        int e = t & 7, l = (t >> 3) & 63;
        int r = t >> 9;
        int ks = r % 6; r /= 6;
        int nf = r & 3; r >>= 2;
        int c  = r & 127;
        int d  = r >> 7;
        int i = nf * 16 + (l & 15);
        int k = ks * 32 + (l >> 4) * 8 + e;
        float val;
        if (k < 64) {
            val = (k <= i) ? Kloc[(d * CC + c) * 64 + (i - k)] : 0.0f;
            if (k == i) val += Dskip[d * CC + c] + 1.0f;
        } else {
            int q = k - 64, n = q >> 1;
            float2 a  = dta[(d * CC + c) * NN + n];
            float2 cb = cb2[(d * CC + c) * NN + n];
            float p   = (float)(i + 1);
            float mag = expf(p * a.x);
            float ang = p * a.y;
            float re = mag * cosf(ang), im = mag * sinf(ang);
            float wre = cb.x * re - cb.y * im;
            float wim = cb.x * im + cb.y * re;
            val = (q & 1) ? -wim : wre;
        }
        W2p[t] = tobf(val);
    }
}

// ---------------------------------------------------------------------------
// x [B,L,C] fp32 -> xt [B][C][L] bf16
// ---------------------------------------------------------------------------
__global__ __launch_bounds__(256) void transpose_kernel(
    const float* __restrict__ x, bf16* __restrict__ xt)
{
    __shared__ float t[64][65];
    int ct = blockIdx.x, lt = blockIdx.y, b = blockIdx.z;
    int tx = threadIdx.x & 63, ty = threadIdx.x >> 6;
    const size_t xbase = ((size_t)b * LL + (size_t)lt * 64) * CC + (size_t)ct * 64;
#pragma unroll
    for (int i = 0; i < 16; ++i)
        t[ty + 4 * i][tx] = x[xbase + (size_t)(ty + 4 * i) * CC + tx];
    __syncthreads();
    const size_t obase = ((size_t)b * CC + (size_t)ct * 64) * LL + (size_t)lt * 64;
#pragma unroll
    for (int i = 0; i < 16; ++i)
        xt[obase + (size_t)(ty + 4 * i) * LL + tx] = tobf(t[tx][ty + 4 * i]);
}

// ---------------------------------------------------------------------------
// STATS: per-(b,l) LayerNorm statistics (mean, rstd) from v [B][C][L] bf16.
// ---------------------------------------------------------------------------
__global__ __launch_bounds__(256) void stats_kernel(
    const bf16* __restrict__ v, float2* __restrict__ st)
{
    __shared__ float rs[4][256];
    __shared__ float rq[4][256];
    int b  = blockIdx.y;
    int l0 = blockIdx.x * 256;
    int lt = threadIdx.x & 63;
    int cg = threadIdx.x >> 6;
    const short* vv = (const short*)v;
    float s[4] = {0.f, 0.f, 0.f, 0.f};
    float q[4] = {0.f, 0.f, 0.f, 0.f};
#pragma unroll
    for (int ci = 0; ci < 32; ++ci) {
        int c = cg * 32 + ci;
        short4v r = *(const short4v*)(&vv[((size_t)b * CC + c) * LL + l0 + lt * 4]);
#pragma unroll
        for (int j = 0; j < 4; ++j) {
            float f = frombits(r[j]);
            s[j] += f;
            q[j] = fmaf(f, f, q[j]);
        }
    }
#pragma unroll
    for (int j = 0; j < 4; ++j) {
        rs[cg][lt * 4 + j] = s[j];
        rq[cg][lt * 4 + j] = q[j];
    }
    __syncthreads();
    if (cg == 0) {
#pragma unroll
        for (int j = 0; j < 4; ++j) {
            int li = lt * 4 + j;
            float ts = rs[0][li] + rs[1][li] + rs[2][li] + rs[3][li];
            float tq = rq[0][li] + rq[1][li] + rq[2][li] + rq[3][li];
            float mean = ts * (1.0f / CC);
            float var  = tq * (1.0f / CC) - mean * mean;
            st[(size_t)b * LL + l0 + li] = make_float2(mean, rsqrtf(var + EPSV));
        }
    }
}

// ---------------------------------------------------------------------------
// KS: block = (c, 8 b's), 512 threads. Weights (40 KB) staged in LDS once.
// Per group: normalize -> phase1 -> [phase3a: ks=0,1 MFMAs] -> prefetch ->
// batched scan -> [phase3b: ks=2..5] -> store. One barrier total.
// ---------------------------------------------------------------------------
__global__ __launch_bounds__(512) void ks_kernel(
    const bf16* __restrict__ u, bf16* __restrict__ v,
    const bf16* __restrict__ Vp, const bf16* __restrict__ W2p,
    const float2* __restrict__ lamT, const float2* __restrict__ st,
    const float* __restrict__ nw, const float* __restrict__ nb)
{
    const int c  = blockIdx.x;             // channel owned by this block
    const int w  = threadIdx.x >> 6;       // wave 0..7 -> b = bg*8+w
    const int l  = threadIdx.x & 63;       // lane: MFMA lane AND mode index n
    const int b  = blockIdx.y * 8 + w;
    const int bc = b * CC + c;
    const bf16* xrow = u + (size_t)bc * LL;
    bf16*       vrow = v + (size_t)bc * LL;

    __shared__ short Wl[8192 + 12288];     // Vp(16KB) + W2p(24KB) = 40 KB
    __shared__ short Sp[8][16 * 136];      // per-wave 4.35 KB scan slice

    // ---- stage weights: 2560 x uint4 across 512 threads, one barrier ----
    {
        uint4*       dst  = (uint4*)Wl;
        const uint4* srcV = (const uint4*)(Vp  + (size_t)c * 8192);
        const uint4* srcW = (const uint4*)(W2p + (size_t)c * 12288);
        int tid = threadIdx.x;
#pragma unroll
        for (int i = 0; i < 2; ++i)
            dst[tid + 512 * i] = srcV[tid + 512 * i];
#pragma unroll
        for (int i = 0; i < 3; ++i)
            dst[1024 + tid + 512 * i] = srcW[tid + 512 * i];
    }
    __syncthreads();                       // the ONLY barrier

    short* S = Sp[w];
    const short* W2l = Wl + 8192;
    const int mloc = l & 15;               // chunk-within-group (MFMA B-col)
    const int koff = (l >> 4) * 8;
    float2 lt = lamT[c * NN + l];
    float sr = 0.f, si = 0.f;              // running state, f32 entire L

    const float2* stb = st ? (st + (size_t)b * LL) : nullptr;
    float wc = 0.f, bcf = 0.f;
    if (st) { wc = nw[c]; bcf = nb[c]; }

    // ---- prefetch group 0's raw x fragments ----
    short8 xf0 = *(const short8*)(xrow + mloc * 64 + koff);
    short8 xf1 = *(const short8*)(xrow + mloc * 64 + koff + 32);

#pragma unroll 1
    for (int g = 0; g < 4; ++g) {
        const int lbase = (g * 16 + mloc) * 64 + koff;

        // ---- normalize current fragments (float4 stat loads) ----
        if (stb) {
            const float4* sq0 = (const float4*)(stb + lbase);
            const float4* sq1 = (const float4*)(stb + lbase + 32);
#pragma unroll
            for (int i = 0; i < 4; ++i) {
                float4 p0 = sq0[i], p1 = sq1[i];
                float a00 = p0.y * wc, a01 = p0.w * wc;
                float a10 = p1.y * wc, a11 = p1.w * wc;
                xf0[2 * i]     = bfbits(fmaf(frombits(xf0[2 * i]),     a00, fmaf(-p0.x, a00, bcf)));
                xf0[2 * i + 1] = bfbits(fmaf(frombits(xf0[2 * i + 1]), a01, fmaf(-p0.z, a01, bcf)));
                xf1[2 * i]     = bfbits(fmaf(frombits(xf1[2 * i]),     a10, fmaf(-p1.x, a10, bcf)));
                xf1[2 * i + 1] = bfbits(fmaf(frombits(xf1[2 * i + 1]), a11, fmaf(-p1.z, a11, bcf)));
            }
        }

        // ---- phase 1 (two 4-nf halves to cap acc pressure) ----
#pragma unroll
        for (int h = 0; h < 2; ++h) {
            f32x4 acc[4];
#pragma unroll
            for (int j = 0; j < 4; ++j) acc[j] = (f32x4){0.f, 0.f, 0.f, 0.f};
#pragma unroll
            for (int j = 0; j < 4; ++j) {
                int nf = h * 4 + j;
                short8 vf0 = *(const short8*)(&Wl[((nf * 2 + 0) * 64 + l) * 8]);
                short8 vf1 = *(const short8*)(&Wl[((nf * 2 + 1) * 64 + l) * 8]);
                acc[j] = MFMA(vf0, xf0, acc[j]);
                acc[j] = MFMA(vf1, xf1, acc[j]);
            }
#pragma unroll
            for (int j = 0; j < 4; ++j) {
                int nf = h * 4 + j;
                short4v t;
                t[0] = bfbits(acc[j][0]); t[1] = bfbits(acc[j][1]);
                t[2] = bfbits(acc[j][2]); t[3] = bfbits(acc[j][3]);
                *(short4v*)(&S[mloc * 136 + nf * 16 + (l >> 4) * 4]) = t;
            }
        }
        asm volatile("" ::: "memory");     // same-wave DS pipe is in-order

        // ---- phase 3a: ks=0,1 (xf-only) — overlaps the scan's stalls ----
        f32x4 o[4];
#pragma unroll
        for (int nf = 0; nf < 4; ++nf) o[nf] = (f32x4){0.f, 0.f, 0.f, 0.f};
#pragma unroll
        for (int nf = 0; nf < 4; ++nf) {
            short8 wf0 = *(const short8*)(&W2l[((nf * 6 + 0) * 64 + l) * 8]);
            o[nf] = MFMA(wf0, xf0, o[nf]);
            short8 wf1 = *(const short8*)(&W2l[((nf * 6 + 1) * 64 + l) * 8]);
            o[nf] = MFMA(wf1, xf1, o[nf]);
        }

        // ---- prefetch next group's raw x fragments ----
        const int gn = (g < 3) ? g + 1 : 3;
        const int lbn = (gn * 16 + mloc) * 64 + koff;
        short8 nxf0 = *(const short8*)(xrow + lbn);
        short8 nxf1 = *(const short8*)(xrow + lbn + 32);

        // ---- scan: batched reads -> VALU chain -> batched writes ----
        uint pk[16];
#pragma unroll
        for (int k = 0; k < 16; ++k)
            pk[k] = *(const uint*)(&S[k * 136 + 2 * l]);
#pragma unroll
        for (int k = 0; k < 16; ++k) {
            uint p = pk[k];
            union { short2 s2; uint uu; } o2;
            o2.s2.x = bfbits(sr); o2.s2.y = bfbits(si);
            pk[k] = o2.uu;                 // Sprev for chunk k
            float pr = __uint_as_float(p << 16);
            float pi = __uint_as_float(p & 0xffff0000u);
            float nr = fmaf(lt.x, sr, fmaf(-lt.y, si, pr));
            si = fmaf(lt.x, si, fmaf(lt.y, sr, pi));
            sr = nr;
        }
#pragma unroll
        for (int k = 0; k < 16; ++k)
            *(uint*)(&S[k * 136 + 2 * l]) = pk[k];
        asm volatile("" ::: "memory");

        // ---- phase 3b: ks=2..5 from Sprev ----
#pragma unroll
        for (int ks = 2; ks < 6; ++ks) {
            short8 xf = *(const short8*)(&S[mloc * 136 + (ks - 2) * 32 + koff]);
#pragma unroll
            for (int nf = 0; nf < 4; ++nf) {
                short8 wf = *(const short8*)(&W2l[((nf * 6 + ks) * 64 + l) * 8]);
                o[nf] = MFMA(wf, xf, o[nf]);
            }
        }
#pragma unroll
        for (int nf = 0; nf < 4; ++nf) {
            short4v t;
            t[0] = bfbits(o[nf][0]); t[1] = bfbits(o[nf][1]);
            t[2] = bfbits(o[nf][2]); t[3] = bfbits(o[nf][3]);
            *(short4v*)(vrow + (g * 16 + mloc) * 64 + nf * 16 + (l >> 4) * 4) = t;
        }

        xf0 = nxf0;                        // rotate prefetched fragments
        xf1 = nxf1;
    }
}

// ---------------------------------------------------------------------------
// LN3: final LayerNorm + head in ONE pass over v.
//   out[b,l] = rstd*( sum_c v*wh_c - mu*S1 ) + S2
// ---------------------------------------------------------------------------
__global__ __launch_bounds__(256) void ln3_kernel(
    const bf16* __restrict__ v,
    const float* __restrict__ w, const float* __restrict__ bta,
    const float* __restrict__ headw, const float* __restrict__ headb,
    float* __restrict__ fout)
{
    __shared__ float rs[4][256];
    __shared__ float rq[4][256];
    __shared__ float rh[4][256];
    __shared__ float r1s[4];
    __shared__ float r2s[4];
    int b  = blockIdx.y;
    int l0 = blockIdx.x * 256;
    int lt = threadIdx.x & 63;
    int cg = threadIdx.x >> 6;
    const short* vv = (const short*)v;
    float s[4] = {0.f, 0.f, 0.f, 0.f};
    float q[4] = {0.f, 0.f, 0.f, 0.f};
    float h[4] = {0.f, 0.f, 0.f, 0.f};
    float ps1 = 0.f, ps2 = 0.f;
#pragma unroll
    for (int ci = 0; ci < 32; ++ci) {
        int c = cg * 32 + ci;
        float hwc = headw[c];
        float whc = w[c] * hwc;
        ps1 += whc;
        ps2 = fmaf(bta[c], hwc, ps2);
        short4v r = *(const short4v*)(&vv[((size_t)b * CC + c) * LL + l0 + lt * 4]);
#pragma unroll
        for (int j = 0; j < 4; ++j) {
            float f = frombits(r[j]);
            s[j] += f;
            q[j] = fmaf(f, f, q[j]);
            h[j] = fmaf(f, whc, h[j]);
        }
    }
#pragma unroll
    for (int j = 0; j < 4; ++j) {
        rs[cg][lt * 4 + j] = s[j];
        rq[cg][lt * 4 + j] = q[j];
        rh[cg][lt * 4 + j] = h[j];
    }
    if (lt == 0) { r1s[cg] = ps1; r2s[cg] = ps2; }
    __syncthreads();
    if (cg == 0) {
        float S1 = r1s[0] + r1s[1] + r1s[2] + r1s[3];
        float S2 = r2s[0] + r2s[1] + r2s[2] + r2s[3] + headb[0];
#pragma unroll
        for (int j = 0; j < 4; ++j) {
            int li = lt * 4 + j;
            float ts = rs[0][li] + rs[1][li] + rs[2][li] + rs[3][li];
            float tq = rq[0][li] + rq[1][li] + rq[2][li] + rq[3][li];
            float th = rh[0][li] + rh[1][li] + rh[2][li] + rh[3][li];
            float mean = ts * (1.0f / CC);
            float var  = tq * (1.0f / CC) - mean * mean;
            float rstd = rsqrtf(var + EPSV);
            fout[(size_t)b * LL + l0 + li] = rstd * (th - mean * S1) + S2;
        }
    }
}

// ---------------------------------------------------------------------------
extern "C" void kernel_launch(void* const* d_in, const int* in_sizes, int n_in,
                              void* d_out, int out_size, void* d_ws, size_t ws_size,
                              hipStream_t stream)
{
    const float* x      = (const float*)d_in[0];
    const float* log_dt = (const float*)d_in[1];
    const float* A_real = (const float*)d_in[2];
    const float* A_imag = (const float*)d_in[3];
    const float* C_re   = (const float*)d_in[4];
    const float* C_im   = (const float*)d_in[5];
    const float* Dskip  = (const float*)d_in[6];
    const float* norm_w = (const float*)d_in[7];
    const float* norm_b = (const float*)d_in[8];
    const float* head_w = (const float*)d_in[9];
    const float* head_b = (const float*)d_in[10];
    float* out = (float*)d_out;

    const size_t DCN = (size_t)DEPTH_ * CC * NN;
    const size_t BCL = (size_t)BB * CC * LL;

    float2* lam  = (float2*)d_ws;
    float2* dta  = lam + DCN;
    float2* cb2  = dta + DCN;
    float2* lamT = cb2 + DCN;
    float*  Kloc = (float*)(lamT + DCN);
    bf16*   A    = (bf16*)(Kloc + (size_t)DEPTH_ * CC * 64);
    bf16*   Bb   = A + BCL;
    bf16*   Vp   = Bb + BCL;
    bf16*   W2p  = Vp + (size_t)DEPTH_ * CC * 8192;
    float2* stbuf = (float2*)(W2p + (size_t)DEPTH_ * CC * 12288);  // B*L float2

    p0_kernel<<<dim3(CC, DEPTH_), 64, 0, stream>>>(
        log_dt, A_real, A_imag, C_re, C_im, lam, dta, cb2, lamT);
    p1_kernel<<<dim3(CC, DEPTH_), 64, 0, stream>>>(cb2, lam, Kloc);
    p2_kernel<<<(DEPTH_ * CC * 8192) / 256 + (DEPTH_ * CC * 12288) / 256,
                256, 0, stream>>>(dta, cb2, Kloc, Dskip, Vp, W2p);
    transpose_kernel<<<dim3(CC / 64, LL / 64, BB), 256, 0, stream>>>(x, A);

    // d=0: A -> Bb (no input norm)
    ks_kernel<<<dim3(CC, BB / 8), 512, 0, stream>>>(
        A, Bb, Vp, W2p, lamT, nullptr, nullptr, nullptr);
    // middle layers: stats then normalized ks
    bf16* src = Bb;
    bf16* dst = A;
    for (int d = 1; d < DEPTH_; ++d) {
        stats_kernel<<<dim3(LL / 256, BB), 256, 0, stream>>>(src, stbuf);
        ks_kernel<<<dim3(CC, BB / 8), 512, 0, stream>>>(
            src, dst, Vp + (size_t)d * CC * 8192, W2p + (size_t)d * CC * 12288,
            lamT + (size_t)d * CC * NN, stbuf,
            norm_w + (d - 1) * CC, norm_b + (d - 1) * CC);
        bf16* tmp = src; src = dst; dst = tmp;
    }
    // final LN + head, one pass
    ln3_kernel<<<dim3(LL / 256, BB), 256, 0, stream>>>(
        src, norm_w + (DEPTH_ - 1) * CC, norm_b + (DEPTH_ - 1) * CC,
        head_w, head_b, out);
}